// Round 28
// baseline (179.253 us; speedup 1.0000x reference)
//
#include <hip/hip_runtime.h>

#define B 8
#define F 257
#define C 8
#define T 800
#define TAPS 5
#define DELAY 3
#define K 40         // TAPS*C
#define NCOL 48      // K + C
#define T0 7         // DELAY + TAPS - 1
#define BF (B*F)     // 2056

typedef __bf16 bf16x8 __attribute__((ext_vector_type(8)));
typedef __bf16 bf16x4 __attribute__((ext_vector_type(4)));
typedef float f32x4 __attribute__((ext_vector_type(4)));

struct PF { float4 v[3]; };

// ---------------- kernel 1: sqrt inverse power weights (0 for t<T0) ----------------
__global__ __launch_bounds__(256) void power_kernel(const float* __restrict__ sr,
                                                    const float* __restrict__ si,
                                                    float* __restrict__ W) {
    int bf = blockIdx.x;
    const float* srp = sr + (size_t)bf * C * T;
    const float* sip = si + (size_t)bf * C * T;
    int t0 = threadIdx.x * 4;
    if (t0 < T) {
        float s[4] = {0.f, 0.f, 0.f, 0.f};
#pragma unroll
        for (int c = 0; c < C; ++c) {
            float4 a = *(const float4*)(srp + c * T + t0);
            float4 b = *(const float4*)(sip + c * T + t0);
            s[0] = fmaf(a.x, a.x, fmaf(b.x, b.x, s[0]));
            s[1] = fmaf(a.y, a.y, fmaf(b.y, b.y, s[1]));
            s[2] = fmaf(a.z, a.z, fmaf(b.z, b.z, s[2]));
            s[3] = fmaf(a.w, a.w, fmaf(b.w, b.w, s[3]));
        }
        float4 w;
        float* wp = (float*)&w;
#pragma unroll
        for (int e = 0; e < 4; ++e) {
            float v = fmaxf(s[e] * (1.0f / C), 1e-7f);
            wp[e] = (t0 + e < T0) ? 0.f : rsqrtf(v);   // sqrt(1/power)
        }
        *(float4*)(W + (size_t)bf * T + t0) = w;
    }
}

// ---------------- kernel 2: R,P via bf16 MFMA — REGISTER-staged (no staging LDS) ----------------
#define WB3 7680

__global__ __launch_bounds__(256, 3) void rp_mfma_kernel(const float* __restrict__ mr,
                                                         const float* __restrict__ mi,
                                                         const float* __restrict__ W,
                                                         float2* __restrict__ Rout,
                                                         float2* __restrict__ Pout) {
    __shared__ __align__(16) unsigned char SH[4 * WB3];
    const int lane = threadIdx.x & 63;
    const int wid = threadIdx.x >> 6;
    const int bf = blockIdx.x * 4 + wid;
    unsigned char* base = SH + wid * WB3;

    const float* mrp = mr + (size_t)bf * C * T;
    const float* mip = mi + (size_t)bf * C * T;
    const float* Wp  = W  + (size_t)bf * T;

    const int q = lane >> 4, col = lane & 15;
    const int pc = lane >> 3, pg = lane & 7;     // phase-B task: channel, 4t-group

    const int PM[6] = {0, 0, 0, 1, 1, 2};
    const int PN[6] = {0, 1, 2, 1, 2, 2};

    // per-lane chunk sources (advance 32 floats per chunk)
    const float* ysr = mrp + pc * T + pg * 4 - 8;
    const float* ysi = mip + pc * T + pg * 4 - 8;
    const float* wsr = Wp + pg * 4;

    f32x4 accRe[6], accIr[6], accRi[6];
#pragma unroll
    for (int p = 0; p < 6; ++p) {
        accRe[p] = (f32x4){0.f, 0.f, 0.f, 0.f};
        accIr[p] = (f32x4){0.f, 0.f, 0.f, 0.f};
        accRi[p] = (f32x4){0.f, 0.f, 0.f, 0.f};
    }

    // prologue: load chunk 0 (halo quads fully below t=0 -> clamp source, zero after)
    float4 yr0, yr1, yr2, yi0, yi1, yi2, wcur;
    {
        const float* cbr = mrp + pc * T;
        const float* cbi = mip + pc * T;
        bool h0 = (pg < 2), h1 = (pg < 1);
        yr0 = *(const float4*)(h0 ? cbr : ysr);
        yr1 = *(const float4*)(h1 ? cbr : (ysr + 4));
        yr2 = *(const float4*)(ysr + 8);
        yi0 = *(const float4*)(h0 ? cbi : ysi);
        yi1 = *(const float4*)(h1 ? cbi : (ysi + 4));
        yi2 = *(const float4*)(ysi + 8);
        wcur = *(const float4*)wsr;
        if (h0) { yr0 = make_float4(0.f,0.f,0.f,0.f); yi0 = make_float4(0.f,0.f,0.f,0.f); }
        if (h1) { yr1 = make_float4(0.f,0.f,0.f,0.f); yi1 = make_float4(0.f,0.f,0.f,0.f); }
    }

    for (int ks = 0; ks < 25; ++ks) {
        // ---- Phase B: build 6 shift-variant bf16 rows from registers ----
        {
            float yre[12], yim[12];
            yre[0] = yr0.x; yre[1] = yr0.y; yre[2]  = yr0.z; yre[3]  = yr0.w;
            yre[4] = yr1.x; yre[5] = yr1.y; yre[6]  = yr1.z; yre[7]  = yr1.w;
            yre[8] = yr2.x; yre[9] = yr2.y; yre[10] = yr2.z; yre[11] = yr2.w;
            yim[0] = yi0.x; yim[1] = yi0.y; yim[2]  = yi0.z; yim[3]  = yi0.w;
            yim[4] = yi1.x; yim[5] = yi1.y; yim[6]  = yi1.z; yim[7]  = yi1.w;
            yim[8] = yi2.x; yim[9] = yi2.y; yim[10] = yi2.z; yim[11] = yi2.w;
            float wv[4] = {wcur.x, wcur.y, wcur.z, wcur.w};
#pragma unroll
            for (int v = 0; v < 6; ++v) {
                int row = (v < 5) ? (v * 8 + pc) : (40 + pc);
                int off = (v < 5) ? (5 - v) : 8;
                bf16x4 zr, zi;
#pragma unroll
                for (int e = 0; e < 4; ++e) {
                    zr[e] = (__bf16)(wv[e] * yre[off + e]);
                    zi[e] = (__bf16)(wv[e] * yim[off + e]);
                }
                *(bf16x4*)(base + row * 80 + pg * 8) = zr;
                *(bf16x4*)(base + 3840 + row * 80 + pg * 8) = zi;
            }
        }

        // ---- issue chunk k+1's register loads (in flight across fragments + MFMA) ----
        float4 nyr0, nyr1, nyr2, nyi0, nyi1, nyi2, nw;
        if (ks < 24) {
            int off = (ks + 1) * 32;
            nyr0 = *(const float4*)(ysr + off);
            nyr1 = *(const float4*)(ysr + off + 4);
            nyr2 = *(const float4*)(ysr + off + 8);
            nyi0 = *(const float4*)(ysi + off);
            nyi1 = *(const float4*)(ysi + off + 4);
            nyi2 = *(const float4*)(ysi + off + 8);
            nw   = *(const float4*)(wsr + off);
        }

        // ---- fragments (shared A/B operand) + 24 MFMA ----
        bf16x8 fr[3], fi[3];
#pragma unroll
        for (int X = 0; X < 3; ++X) {
            fr[X] = *(const bf16x8*)(base + (X * 16 + col) * 80 + q * 16);
            fi[X] = *(const bf16x8*)(base + 3840 + (X * 16 + col) * 80 + q * 16);
        }
#pragma unroll
        for (int p = 0; p < 6; ++p) {
            int mt = PM[p], nt = PN[p];
            accRe[p] = __builtin_amdgcn_mfma_f32_16x16x32_bf16(fr[mt], fr[nt], accRe[p], 0, 0, 0);
            accRe[p] = __builtin_amdgcn_mfma_f32_16x16x32_bf16(fi[mt], fi[nt], accRe[p], 0, 0, 0);
            accIr[p] = __builtin_amdgcn_mfma_f32_16x16x32_bf16(fi[mt], fr[nt], accIr[p], 0, 0, 0);
            accRi[p] = __builtin_amdgcn_mfma_f32_16x16x32_bf16(fr[mt], fi[nt], accRi[p], 0, 0, 0);
        }

        if (ks < 24) {
            yr0 = nyr0; yr1 = nyr1; yr2 = nyr2;
            yi0 = nyi0; yi1 = nyi1; yi2 = nyi2;
            wcur = nw;
        }
    }

    // ---- epilogue: D row=(lane>>4)*4+reg, col=lane&15 (m89); Hermitian mirror ----
    // EPS_REG added on the diagonal here.
    float2* Rp = Rout + (size_t)bf * K * K;
    float2* Pp = Pout + (size_t)bf * K * C;
#pragma unroll
    for (int p = 0; p < 6; ++p) {
        int mt = PM[p], nt = PN[p];
#pragma unroll
        for (int r = 0; r < 4; ++r) {
            int m = mt * 16 + q * 4 + r;
            int n = nt * 16 + col;
            float re = accRe[p][r];
            float im = accIr[p][r] - accRi[p][r];
            if (m < K) {
                if (n < K) {
                    if (m == n) re += 1e-10f;
                    Rp[m * K + n] = make_float2(re, im);
                } else {
                    Pp[m * C + (n - K)] = make_float2(re, im);
                }
            }
            if (mt != nt && m < K && n < K)
                Rp[n * K + m] = make_float2(re, -im);
        }
    }
}

// ---------------- kernel 3: solve — column-split cooperative GJ, 4 waves/system ----------------
__device__ __forceinline__ float rdlane(float v, int j) {
    return __uint_as_float(__builtin_amdgcn_readlane(__float_as_uint(v), (unsigned)j));
}

__global__ __launch_bounds__(256) void solve_kernel(const float2* __restrict__ Rin,
                                                    const float2* __restrict__ Pin,
                                                    float2* __restrict__ Gout) {
    __shared__ float2 lbuf[2][64];
    const int bf = blockIdx.x;
    const int lane = threadIdx.x & 63;
    const int w = threadIdx.x >> 6;
    const bool act = lane < K;
    const int lr = act ? lane : 0;

    float2 colw[12];
    {
        const float2* Arow = Rin + (size_t)bf * K * K + (size_t)lr * K;
        const float2* Prow = Pin + (size_t)bf * K * C + (size_t)lr * C;
#pragma unroll
        for (int m = 0; m < 10; ++m) {
            float2 v = Arow[4 * m + w];
            colw[m] = act ? v : make_float2(0.f, 0.f);
        }
#pragma unroll
        for (int m = 10; m < 12; ++m) {
            float2 v = Prow[4 * (m - 10) + w];
            colw[m] = act ? v : make_float2(0.f, 0.f);
        }
    }

#pragma unroll
    for (int j = 0; j < K; ++j) {
        const int par = j & 1;
        const int wo = j & 3;       // owner wave (static)
        const int mj = j >> 2;      // owner's local pivot column (static)
        if (w == wo) {
            float dx = rdlane(colw[mj].x, j);
            float dy = rdlane(colw[mj].y, j);
            float den = fmaf(dx, dx, dy * dy);
            float r = 1.0f / den;
            float ix = dx * r, iy = -dy * r;
            float lx = colw[mj].x * ix - colw[mj].y * iy;
            float ly = colw[mj].x * iy + colw[mj].y * ix;
            bool isj = (lane == j);
            lx = isj ? (1.0f - ix) : lx;
            ly = isj ? (0.0f - iy) : ly;
            lbuf[par][lane] = make_float2(lx, ly);
        }
        __syncthreads();
        float2 l = lbuf[par][lane];
#pragma unroll
        for (int m = 0; m < 12; ++m) {
            if (4 * m + 3 <= j) continue;            // statically dead for all waves
            bool doit = (4 * m > j) || (4 * m + w > j);  // first term static
            if (doit) {
                float ux = rdlane(colw[m].x, j);
                float uy = rdlane(colw[m].y, j);
                colw[m].x = fmaf(-l.x, ux, fmaf( l.y, uy, colw[m].x));
                colw[m].y = fmaf(-l.x, uy, fmaf(-l.y, ux, colw[m].y));
            }
        }
    }

    if (act) {
        float2* Gp = Gout + (size_t)bf * K * C + (size_t)lane * C;
        Gp[w]     = colw[10];
        Gp[4 + w] = colw[11];
    }
}

// ---------------- kernel 4: X via bf16 MFMA — 8-way t-split for occupancy ----------------
#define XSTR 144
#define XWB 12032

__device__ __forceinline__ PF x_load(const float* __restrict__ mrp,
                                     const float* __restrict__ mip,
                                     int tb, int lane) {
    PF p;
#pragma unroll
    for (int it = 0; it < 3; ++it) {
        int task = lane + it * 64;
        float4 v = make_float4(0.f, 0.f, 0.f, 0.f);
        if (task < 160) {
            int pl = task / 80;
            int rem = task - pl * 80;
            int c = rem / 10, grp = rem - c * 10;
            int tg = tb - 8 + grp * 4;
            const float* srcp = pl ? mip : mrp;
            if (tg >= 0) v = *(const float4*)(srcp + c * T + tg);
        }
        p.v[it] = v;
    }
    return p;
}

__device__ __forceinline__ void x_store(const PF& p, float* sre, float* sim_, int lane) {
#pragma unroll
    for (int it = 0; it < 3; ++it) {
        int task = lane + it * 64;
        if (task < 160) {
            int pl = task / 80;
            int rem = task - pl * 80;
            int c = rem / 10, grp = rem - c * 10;
            *(float4*)((pl ? sim_ : sre) + c * 44 + grp * 4) = p.v[it];
        }
    }
}

__global__ __launch_bounds__(64) void x_mfma_kernel(const float* __restrict__ mr,
                                                    const float* __restrict__ mi,
                                                    const float2* __restrict__ Gin,
                                                    const int* __restrict__ ilens,
                                                    float2* __restrict__ out) {
    __shared__ __align__(16) unsigned char SH[XWB];
    const int lane = threadIdx.x;
    const int gid = blockIdx.x;
    const int bf = gid >> 3;
    const int split = gid & 7;
    // chunk ranges: split 0 -> {0..3}, splits 1..7 -> 3 chunks each (4 + 7*3 = 25)
    const int ck0 = (split == 0) ? 0 : (4 + (split - 1) * 3);
    const int nck = (split == 0) ? 4 : 3;
    unsigned char* base = SH;
    float* sre = (float*)(base + 9216);
    float* sim_ = (float*)(base + 10624);

    const float* mrp = mr + (size_t)bf * C * T;
    const float* mip = mi + (size_t)bf * C * T;
    const float2* Gp = Gin + (size_t)bf * K * C;
    float2* outp = out + (size_t)bf * C * T;
    const int len = ilens[bf / F];

    const int q = lane >> 4, col = lane & 15;
    const int t2 = lane >> 1, half = lane & 1;

    // ---- one-time: zero-fill bytes [80,128) of all rows (a = 40..63 -> 0.0) ----
#pragma unroll
    for (int pl = 0; pl < 2; ++pl) {
        unsigned char* pb = base + pl * 4608 + t2 * XSTR + 80 + half * 24;
        *(float2*)(pb)      = make_float2(0.f, 0.f);
        *(float2*)(pb + 8)  = make_float2(0.f, 0.f);
        *(float2*)(pb + 16) = make_float2(0.f, 0.f);
    }

    // ---- A fragments: G (and -Gi) in registers, built once ----
    bf16x8 Agr[2], Agi[2], Agin[2];
#pragma unroll
    for (int ks = 0; ks < 2; ++ks)
#pragma unroll
        for (int j = 0; j < 8; ++j) {
            int a = ks * 32 + q * 8 + j;
            float2 g = make_float2(0.f, 0.f);
            if (a < K && col < C) g = Gp[a * C + col];
            Agr[ks][j]  = (__bf16)g.x;
            Agi[ks][j]  = (__bf16)g.y;
            Agin[ks][j] = (__bf16)(-g.y);
        }

    PF cur = x_load(mrp, mip, ck0 * 32, lane);

    for (int ci = 0; ci < nck; ++ci) {
        const int tb = (ck0 + ci) * 32;

        // ---- write staged chunk; prefetch next ----
        x_store(cur, sre, sim_, lane);
        if (ci + 1 < nck) cur = x_load(mrp, mip, tb + 32, lane);

        // ---- Phase B: build transposed bf16 Ytilde rows [t_local][a] ----
#pragma unroll
        for (int i = 0; i < 5; ++i) {
            int abase = half * 20 + 4 * i;
            bf16x4 zr, zi;
#pragma unroll
            for (int e2 = 0; e2 < 4; ++e2) {
                int a = abase + e2;
                int v = a >> 3, c = a & 7;
                int idx = c * 44 + t2 + 5 - v;   // Y[c][tb+t2-3-v]
                zr[e2] = (__bf16)sre[idx];
                zi[e2] = (__bf16)sim_[idx];
            }
            *(bf16x4*)(base + t2 * XSTR + abase * 2) = zr;
            *(bf16x4*)(base + 4608 + t2 * XSTR + abase * 2) = zi;
        }

        // ---- two 16-t tiles: 8 MFMA each + epilogue (Y from scratch LDS) ----
#pragma unroll
        for (int tt = 0; tt < 2; ++tt) {
            const int trow = tt * 16 + col;
            f32x4 accRe = (f32x4){0.f, 0.f, 0.f, 0.f};
            f32x4 accIm = (f32x4){0.f, 0.f, 0.f, 0.f};
#pragma unroll
            for (int ks = 0; ks < 2; ++ks) {
                bf16x8 byr = *(const bf16x8*)(base + trow * XSTR + ks * 64 + q * 16);
                bf16x8 byi = *(const bf16x8*)(base + 4608 + trow * XSTR + ks * 64 + q * 16);
                accRe = __builtin_amdgcn_mfma_f32_16x16x32_bf16(Agr[ks], byr, accRe, 0, 0, 0);
                accRe = __builtin_amdgcn_mfma_f32_16x16x32_bf16(Agi[ks], byi, accRe, 0, 0, 0);
                accIm = __builtin_amdgcn_mfma_f32_16x16x32_bf16(Agr[ks], byi, accIm, 0, 0, 0);
                accIm = __builtin_amdgcn_mfma_f32_16x16x32_bf16(Agin[ks], byr, accIm, 0, 0, 0);
            }
            // D row=(lane>>4)*4+r (=e), col=lane&15 (=t offset) [m89]
            if (q < 2) {
                int t = tb + tt * 16 + col;
                int l = tt * 16 + col + 8;       // scratch index of t
                bool ok = (t < len);
#pragma unroll
                for (int r = 0; r < 4; ++r) {
                    int e = q * 4 + r;
                    float yr = sre[e * 44 + l];
                    float yi = sim_[e * 44 + l];
                    float2 v = ok ? make_float2(yr - accRe[r], yi - accIm[r])
                                  : make_float2(0.f, 0.f);
                    outp[e * T + t] = v;
                }
            }
        }
    }
}

extern "C" void kernel_launch(void* const* d_in, const int* in_sizes, int n_in,
                              void* d_out, int out_size, void* d_ws, size_t ws_size,
                              hipStream_t stream) {
    const float* sep_r = (const float*)d_in[0];
    const float* sep_i = (const float*)d_in[1];
    const float* mix_r = (const float*)d_in[2];
    const float* mix_i = (const float*)d_in[3];
    const int* ilens   = (const int*)d_in[4];

    float* ws = (float*)d_ws;
    float* W = ws;                                        // BF*T floats
    float2* Rws = (float2*)(ws + (size_t)BF * T);         // BF*K*K float2
    float2* Gws = Rws + (size_t)BF * K * K;               // BF*K*C float2 (P then G in-place)

    power_kernel<<<BF, 256, 0, stream>>>(sep_r, sep_i, W);
    rp_mfma_kernel<<<BF / 4, 256, 0, stream>>>(mix_r, mix_i, W, Rws, Gws);
    solve_kernel<<<BF, 256, 0, stream>>>(Rws, Gws, Gws);
    x_mfma_kernel<<<BF * 8, 64, 0, stream>>>(mix_r, mix_i, Gws, ilens, (float2*)d_out);
}

// Round 29
// 153.778 us; speedup vs baseline: 1.1657x; 1.1657x over previous
//
#include <hip/hip_runtime.h>

#define B 8
#define F 257
#define C 8
#define T 800
#define TAPS 5
#define DELAY 3
#define K 40         // TAPS*C
#define NCOL 48      // K + C
#define T0 7         // DELAY + TAPS - 1
#define BF (B*F)     // 2056

typedef __bf16 bf16x8 __attribute__((ext_vector_type(8)));
typedef __bf16 bf16x4 __attribute__((ext_vector_type(4)));
typedef float f32x4 __attribute__((ext_vector_type(4)));

struct PF { float4 v[3]; };

// ---------------- kernel 1: sqrt inverse power weights (0 for t<T0) ----------------
__global__ __launch_bounds__(256) void power_kernel(const float* __restrict__ sr,
                                                    const float* __restrict__ si,
                                                    float* __restrict__ W) {
    int bf = blockIdx.x;
    const float* srp = sr + (size_t)bf * C * T;
    const float* sip = si + (size_t)bf * C * T;
    int t0 = threadIdx.x * 4;
    if (t0 < T) {
        float s[4] = {0.f, 0.f, 0.f, 0.f};
#pragma unroll
        for (int c = 0; c < C; ++c) {
            float4 a = *(const float4*)(srp + c * T + t0);
            float4 b = *(const float4*)(sip + c * T + t0);
            s[0] = fmaf(a.x, a.x, fmaf(b.x, b.x, s[0]));
            s[1] = fmaf(a.y, a.y, fmaf(b.y, b.y, s[1]));
            s[2] = fmaf(a.z, a.z, fmaf(b.z, b.z, s[2]));
            s[3] = fmaf(a.w, a.w, fmaf(b.w, b.w, s[3]));
        }
        float4 w;
        float* wp = (float*)&w;
#pragma unroll
        for (int e = 0; e < 4; ++e) {
            float v = fmaxf(s[e] * (1.0f / C), 1e-7f);
            wp[e] = (t0 + e < T0) ? 0.f : rsqrtf(v);   // sqrt(1/power)
        }
        *(float4*)(W + (size_t)bf * T + t0) = w;
    }
}

// ---------------- kernel 2: R,P via bf16 MFMA — REGISTER-staged (no staging LDS) ----------------
#define WB3 7680

__global__ __launch_bounds__(256, 3) void rp_mfma_kernel(const float* __restrict__ mr,
                                                         const float* __restrict__ mi,
                                                         const float* __restrict__ W,
                                                         float2* __restrict__ Rout,
                                                         float2* __restrict__ Pout) {
    __shared__ __align__(16) unsigned char SH[4 * WB3];
    const int lane = threadIdx.x & 63;
    const int wid = threadIdx.x >> 6;
    const int bf = blockIdx.x * 4 + wid;
    unsigned char* base = SH + wid * WB3;

    const float* mrp = mr + (size_t)bf * C * T;
    const float* mip = mi + (size_t)bf * C * T;
    const float* Wp  = W  + (size_t)bf * T;

    const int q = lane >> 4, col = lane & 15;
    const int pc = lane >> 3, pg = lane & 7;     // phase-B task: channel, 4t-group

    const int PM[6] = {0, 0, 0, 1, 1, 2};
    const int PN[6] = {0, 1, 2, 1, 2, 2};

    // per-lane chunk sources (advance 32 floats per chunk)
    const float* ysr = mrp + pc * T + pg * 4 - 8;
    const float* ysi = mip + pc * T + pg * 4 - 8;
    const float* wsr = Wp + pg * 4;

    f32x4 accRe[6], accIr[6], accRi[6];
#pragma unroll
    for (int p = 0; p < 6; ++p) {
        accRe[p] = (f32x4){0.f, 0.f, 0.f, 0.f};
        accIr[p] = (f32x4){0.f, 0.f, 0.f, 0.f};
        accRi[p] = (f32x4){0.f, 0.f, 0.f, 0.f};
    }

    // prologue: load chunk 0 (halo quads fully below t=0 -> clamp source, zero after)
    float4 yr0, yr1, yr2, yi0, yi1, yi2, wcur;
    {
        const float* cbr = mrp + pc * T;
        const float* cbi = mip + pc * T;
        bool h0 = (pg < 2), h1 = (pg < 1);
        yr0 = *(const float4*)(h0 ? cbr : ysr);
        yr1 = *(const float4*)(h1 ? cbr : (ysr + 4));
        yr2 = *(const float4*)(ysr + 8);
        yi0 = *(const float4*)(h0 ? cbi : ysi);
        yi1 = *(const float4*)(h1 ? cbi : (ysi + 4));
        yi2 = *(const float4*)(ysi + 8);
        wcur = *(const float4*)wsr;
        if (h0) { yr0 = make_float4(0.f,0.f,0.f,0.f); yi0 = make_float4(0.f,0.f,0.f,0.f); }
        if (h1) { yr1 = make_float4(0.f,0.f,0.f,0.f); yi1 = make_float4(0.f,0.f,0.f,0.f); }
    }

    for (int ks = 0; ks < 25; ++ks) {
        // ---- Phase B: build 6 shift-variant bf16 rows from registers ----
        {
            float yre[12], yim[12];
            yre[0] = yr0.x; yre[1] = yr0.y; yre[2]  = yr0.z; yre[3]  = yr0.w;
            yre[4] = yr1.x; yre[5] = yr1.y; yre[6]  = yr1.z; yre[7]  = yr1.w;
            yre[8] = yr2.x; yre[9] = yr2.y; yre[10] = yr2.z; yre[11] = yr2.w;
            yim[0] = yi0.x; yim[1] = yi0.y; yim[2]  = yi0.z; yim[3]  = yi0.w;
            yim[4] = yi1.x; yim[5] = yi1.y; yim[6]  = yi1.z; yim[7]  = yi1.w;
            yim[8] = yi2.x; yim[9] = yi2.y; yim[10] = yi2.z; yim[11] = yi2.w;
            float wv[4] = {wcur.x, wcur.y, wcur.z, wcur.w};
#pragma unroll
            for (int v = 0; v < 6; ++v) {
                int row = (v < 5) ? (v * 8 + pc) : (40 + pc);
                int off = (v < 5) ? (5 - v) : 8;
                bf16x4 zr, zi;
#pragma unroll
                for (int e = 0; e < 4; ++e) {
                    zr[e] = (__bf16)(wv[e] * yre[off + e]);
                    zi[e] = (__bf16)(wv[e] * yim[off + e]);
                }
                *(bf16x4*)(base + row * 80 + pg * 8) = zr;
                *(bf16x4*)(base + 3840 + row * 80 + pg * 8) = zi;
            }
        }

        // ---- issue chunk k+1's register loads (in flight across fragments + MFMA) ----
        float4 nyr0, nyr1, nyr2, nyi0, nyi1, nyi2, nw;
        if (ks < 24) {
            int off = (ks + 1) * 32;
            nyr0 = *(const float4*)(ysr + off);
            nyr1 = *(const float4*)(ysr + off + 4);
            nyr2 = *(const float4*)(ysr + off + 8);
            nyi0 = *(const float4*)(ysi + off);
            nyi1 = *(const float4*)(ysi + off + 4);
            nyi2 = *(const float4*)(ysi + off + 8);
            nw   = *(const float4*)(wsr + off);
        }

        // ---- fragments (shared A/B operand) + 24 MFMA ----
        bf16x8 fr[3], fi[3];
#pragma unroll
        for (int X = 0; X < 3; ++X) {
            fr[X] = *(const bf16x8*)(base + (X * 16 + col) * 80 + q * 16);
            fi[X] = *(const bf16x8*)(base + 3840 + (X * 16 + col) * 80 + q * 16);
        }
#pragma unroll
        for (int p = 0; p < 6; ++p) {
            int mt = PM[p], nt = PN[p];
            accRe[p] = __builtin_amdgcn_mfma_f32_16x16x32_bf16(fr[mt], fr[nt], accRe[p], 0, 0, 0);
            accRe[p] = __builtin_amdgcn_mfma_f32_16x16x32_bf16(fi[mt], fi[nt], accRe[p], 0, 0, 0);
            accIr[p] = __builtin_amdgcn_mfma_f32_16x16x32_bf16(fi[mt], fr[nt], accIr[p], 0, 0, 0);
            accRi[p] = __builtin_amdgcn_mfma_f32_16x16x32_bf16(fr[mt], fi[nt], accRi[p], 0, 0, 0);
        }

        if (ks < 24) {
            yr0 = nyr0; yr1 = nyr1; yr2 = nyr2;
            yi0 = nyi0; yi1 = nyi1; yi2 = nyi2;
            wcur = nw;
        }
    }

    // ---- epilogue: D row=(lane>>4)*4+reg, col=lane&15 (m89); Hermitian mirror ----
    // EPS_REG added on the diagonal here.
    float2* Rp = Rout + (size_t)bf * K * K;
    float2* Pp = Pout + (size_t)bf * K * C;
#pragma unroll
    for (int p = 0; p < 6; ++p) {
        int mt = PM[p], nt = PN[p];
#pragma unroll
        for (int r = 0; r < 4; ++r) {
            int m = mt * 16 + q * 4 + r;
            int n = nt * 16 + col;
            float re = accRe[p][r];
            float im = accIr[p][r] - accRi[p][r];
            if (m < K) {
                if (n < K) {
                    if (m == n) re += 1e-10f;
                    Rp[m * K + n] = make_float2(re, im);
                } else {
                    Pp[m * C + (n - K)] = make_float2(re, im);
                }
            }
            if (mt != nt && m < K && n < K)
                Rp[n * K + m] = make_float2(re, -im);
        }
    }
}

// ---------------- kernel 3: solve — column-split cooperative GJ, 4 waves/system ----------------
__device__ __forceinline__ float rdlane(float v, int j) {
    return __uint_as_float(__builtin_amdgcn_readlane(__float_as_uint(v), (unsigned)j));
}

__global__ __launch_bounds__(256) void solve_kernel(const float2* __restrict__ Rin,
                                                    const float2* __restrict__ Pin,
                                                    float2* __restrict__ Gout) {
    __shared__ float2 lbuf[2][64];
    const int bf = blockIdx.x;
    const int lane = threadIdx.x & 63;
    const int w = threadIdx.x >> 6;
    const bool act = lane < K;
    const int lr = act ? lane : 0;

    float2 colw[12];
    {
        const float2* Arow = Rin + (size_t)bf * K * K + (size_t)lr * K;
        const float2* Prow = Pin + (size_t)bf * K * C + (size_t)lr * C;
#pragma unroll
        for (int m = 0; m < 10; ++m) {
            float2 v = Arow[4 * m + w];
            colw[m] = act ? v : make_float2(0.f, 0.f);
        }
#pragma unroll
        for (int m = 10; m < 12; ++m) {
            float2 v = Prow[4 * (m - 10) + w];
            colw[m] = act ? v : make_float2(0.f, 0.f);
        }
    }

#pragma unroll
    for (int j = 0; j < K; ++j) {
        const int par = j & 1;
        const int wo = j & 3;       // owner wave (static)
        const int mj = j >> 2;      // owner's local pivot column (static)
        if (w == wo) {
            float dx = rdlane(colw[mj].x, j);
            float dy = rdlane(colw[mj].y, j);
            float den = fmaf(dx, dx, dy * dy);
            float r = 1.0f / den;
            float ix = dx * r, iy = -dy * r;
            float lx = colw[mj].x * ix - colw[mj].y * iy;
            float ly = colw[mj].x * iy + colw[mj].y * ix;
            bool isj = (lane == j);
            lx = isj ? (1.0f - ix) : lx;
            ly = isj ? (0.0f - iy) : ly;
            lbuf[par][lane] = make_float2(lx, ly);
        }
        __syncthreads();
        float2 l = lbuf[par][lane];
#pragma unroll
        for (int m = 0; m < 12; ++m) {
            if (4 * m + 3 <= j) continue;            // statically dead for all waves
            bool doit = (4 * m > j) || (4 * m + w > j);  // first term static
            if (doit) {
                float ux = rdlane(colw[m].x, j);
                float uy = rdlane(colw[m].y, j);
                colw[m].x = fmaf(-l.x, ux, fmaf( l.y, uy, colw[m].x));
                colw[m].y = fmaf(-l.x, uy, fmaf(-l.y, ux, colw[m].y));
            }
        }
    }

    if (act) {
        float2* Gp = Gout + (size_t)bf * K * C + (size_t)lane * C;
        Gp[w]     = colw[10];
        Gp[4 + w] = colw[11];
    }
}

// ---------------- kernel 4: X via bf16 MFMA — 4 splits of one bf packed per block ----------------
// Block = 256 thr = 4 waves; wave wid handles split wid of bf = blockIdx.x (wave-private
// LDS region, NO barriers). Same per-wave code as the R26 best; packing tests whether the
// 8-blocks/CU slot cap (occupancy 25%) was the binder: 3 blocks/CU x 4 waves = 12 waves.
#define XSTR 144
#define XWB 12032

__device__ __forceinline__ PF x_load(const float* __restrict__ mrp,
                                     const float* __restrict__ mip,
                                     int tb, int lane) {
    PF p;
#pragma unroll
    for (int it = 0; it < 3; ++it) {
        int task = lane + it * 64;
        float4 v = make_float4(0.f, 0.f, 0.f, 0.f);
        if (task < 160) {
            int pl = task / 80;
            int rem = task - pl * 80;
            int c = rem / 10, grp = rem - c * 10;
            int tg = tb - 8 + grp * 4;
            const float* srcp = pl ? mip : mrp;
            if (tg >= 0) v = *(const float4*)(srcp + c * T + tg);
        }
        p.v[it] = v;
    }
    return p;
}

__device__ __forceinline__ void x_store(const PF& p, float* sre, float* sim_, int lane) {
#pragma unroll
    for (int it = 0; it < 3; ++it) {
        int task = lane + it * 64;
        if (task < 160) {
            int pl = task / 80;
            int rem = task - pl * 80;
            int c = rem / 10, grp = rem - c * 10;
            *(float4*)((pl ? sim_ : sre) + c * 44 + grp * 4) = p.v[it];
        }
    }
}

__global__ __launch_bounds__(256) void x_mfma_kernel(const float* __restrict__ mr,
                                                     const float* __restrict__ mi,
                                                     const float2* __restrict__ Gin,
                                                     const int* __restrict__ ilens,
                                                     float2* __restrict__ out) {
    __shared__ __align__(16) unsigned char SH[4 * XWB];
    const int lane = threadIdx.x & 63;
    const int split = threadIdx.x >> 6;
    const int bf = blockIdx.x;
    const int ck0 = (split == 0) ? 0 : (1 + split * 6);
    const int nck = (split == 0) ? 7 : 6;
    unsigned char* base = SH + split * XWB;
    float* sre = (float*)(base + 9216);
    float* sim_ = (float*)(base + 10624);

    const float* mrp = mr + (size_t)bf * C * T;
    const float* mip = mi + (size_t)bf * C * T;
    const float2* Gp = Gin + (size_t)bf * K * C;
    float2* outp = out + (size_t)bf * C * T;
    const int len = ilens[bf / F];

    const int q = lane >> 4, col = lane & 15;
    const int t2 = lane >> 1, half = lane & 1;

    // ---- one-time: zero-fill bytes [80,128) of all rows (a = 40..63 -> 0.0) ----
#pragma unroll
    for (int pl = 0; pl < 2; ++pl) {
        unsigned char* pb = base + pl * 4608 + t2 * XSTR + 80 + half * 24;
        *(float2*)(pb)      = make_float2(0.f, 0.f);
        *(float2*)(pb + 8)  = make_float2(0.f, 0.f);
        *(float2*)(pb + 16) = make_float2(0.f, 0.f);
    }

    // ---- A fragments: G (and -Gi) in registers, built once ----
    bf16x8 Agr[2], Agi[2], Agin[2];
#pragma unroll
    for (int ks = 0; ks < 2; ++ks)
#pragma unroll
        for (int j = 0; j < 8; ++j) {
            int a = ks * 32 + q * 8 + j;
            float2 g = make_float2(0.f, 0.f);
            if (a < K && col < C) g = Gp[a * C + col];
            Agr[ks][j]  = (__bf16)g.x;
            Agi[ks][j]  = (__bf16)g.y;
            Agin[ks][j] = (__bf16)(-g.y);
        }

    PF cur = x_load(mrp, mip, ck0 * 32, lane);

    for (int ci = 0; ci < nck; ++ci) {
        const int tb = (ck0 + ci) * 32;

        // ---- write staged chunk; prefetch next ----
        x_store(cur, sre, sim_, lane);
        if (ci + 1 < nck) cur = x_load(mrp, mip, tb + 32, lane);

        // ---- Phase B: build transposed bf16 Ytilde rows [t_local][a] ----
#pragma unroll
        for (int i = 0; i < 5; ++i) {
            int abase = half * 20 + 4 * i;
            bf16x4 zr, zi;
#pragma unroll
            for (int e2 = 0; e2 < 4; ++e2) {
                int a = abase + e2;
                int v = a >> 3, c = a & 7;
                int idx = c * 44 + t2 + 5 - v;   // Y[c][tb+t2-3-v]
                zr[e2] = (__bf16)sre[idx];
                zi[e2] = (__bf16)sim_[idx];
            }
            *(bf16x4*)(base + t2 * XSTR + abase * 2) = zr;
            *(bf16x4*)(base + 4608 + t2 * XSTR + abase * 2) = zi;
        }

        // ---- two 16-t tiles: 8 MFMA each + epilogue (Y from scratch LDS) ----
#pragma unroll
        for (int tt = 0; tt < 2; ++tt) {
            const int trow = tt * 16 + col;
            f32x4 accRe = (f32x4){0.f, 0.f, 0.f, 0.f};
            f32x4 accIm = (f32x4){0.f, 0.f, 0.f, 0.f};
#pragma unroll
            for (int ks = 0; ks < 2; ++ks) {
                bf16x8 byr = *(const bf16x8*)(base + trow * XSTR + ks * 64 + q * 16);
                bf16x8 byi = *(const bf16x8*)(base + 4608 + trow * XSTR + ks * 64 + q * 16);
                accRe = __builtin_amdgcn_mfma_f32_16x16x32_bf16(Agr[ks], byr, accRe, 0, 0, 0);
                accRe = __builtin_amdgcn_mfma_f32_16x16x32_bf16(Agi[ks], byi, accRe, 0, 0, 0);
                accIm = __builtin_amdgcn_mfma_f32_16x16x32_bf16(Agr[ks], byi, accIm, 0, 0, 0);
                accIm = __builtin_amdgcn_mfma_f32_16x16x32_bf16(Agin[ks], byr, accIm, 0, 0, 0);
            }
            // D row=(lane>>4)*4+r (=e), col=lane&15 (=t offset) [m89]
            if (q < 2) {
                int t = tb + tt * 16 + col;
                int l = tt * 16 + col + 8;       // scratch index of t
                bool ok = (t < len);
#pragma unroll
                for (int r = 0; r < 4; ++r) {
                    int e = q * 4 + r;
                    float yr = sre[e * 44 + l];
                    float yi = sim_[e * 44 + l];
                    float2 v = ok ? make_float2(yr - accRe[r], yi - accIm[r])
                                  : make_float2(0.f, 0.f);
                    outp[e * T + t] = v;
                }
            }
        }
    }
}

extern "C" void kernel_launch(void* const* d_in, const int* in_sizes, int n_in,
                              void* d_out, int out_size, void* d_ws, size_t ws_size,
                              hipStream_t stream) {
    const float* sep_r = (const float*)d_in[0];
    const float* sep_i = (const float*)d_in[1];
    const float* mix_r = (const float*)d_in[2];
    const float* mix_i = (const float*)d_in[3];
    const int* ilens   = (const int*)d_in[4];

    float* ws = (float*)d_ws;
    float* W = ws;                                        // BF*T floats
    float2* Rws = (float2*)(ws + (size_t)BF * T);         // BF*K*K float2
    float2* Gws = Rws + (size_t)BF * K * K;               // BF*K*C float2 (P then G in-place)

    power_kernel<<<BF, 256, 0, stream>>>(sep_r, sep_i, W);
    rp_mfma_kernel<<<BF / 4, 256, 0, stream>>>(mix_r, mix_i, W, Rws, Gws);
    solve_kernel<<<BF, 256, 0, stream>>>(Rws, Gws, Gws);
    x_mfma_kernel<<<BF, 256, 0, stream>>>(mix_r, mix_i, Gws, ilens, (float2*)d_out);
}

// Round 30
// 153.523 us; speedup vs baseline: 1.1676x; 1.0017x over previous
//
#include <hip/hip_runtime.h>

#define B 8
#define F 257
#define C 8
#define T 800
#define TAPS 5
#define DELAY 3
#define K 40         // TAPS*C
#define NCOL 48      // K + C
#define T0 7         // DELAY + TAPS - 1
#define BF (B*F)     // 2056

typedef __bf16 bf16x8 __attribute__((ext_vector_type(8)));
typedef __bf16 bf16x4 __attribute__((ext_vector_type(4)));
typedef float f32x4 __attribute__((ext_vector_type(4)));

struct PF { float4 v[3]; };

// ---------------- kernel 1: sqrt inverse power weights (0 for t<T0) ----------------
__global__ __launch_bounds__(256) void power_kernel(const float* __restrict__ sr,
                                                    const float* __restrict__ si,
                                                    float* __restrict__ W) {
    int bf = blockIdx.x;
    const float* srp = sr + (size_t)bf * C * T;
    const float* sip = si + (size_t)bf * C * T;
    int t0 = threadIdx.x * 4;
    if (t0 < T) {
        float s[4] = {0.f, 0.f, 0.f, 0.f};
#pragma unroll
        for (int c = 0; c < C; ++c) {
            float4 a = *(const float4*)(srp + c * T + t0);
            float4 b = *(const float4*)(sip + c * T + t0);
            s[0] = fmaf(a.x, a.x, fmaf(b.x, b.x, s[0]));
            s[1] = fmaf(a.y, a.y, fmaf(b.y, b.y, s[1]));
            s[2] = fmaf(a.z, a.z, fmaf(b.z, b.z, s[2]));
            s[3] = fmaf(a.w, a.w, fmaf(b.w, b.w, s[3]));
        }
        float4 w;
        float* wp = (float*)&w;
#pragma unroll
        for (int e = 0; e < 4; ++e) {
            float v = fmaxf(s[e] * (1.0f / C), 1e-7f);
            wp[e] = (t0 + e < T0) ? 0.f : rsqrtf(v);   // sqrt(1/power)
        }
        *(float4*)(W + (size_t)bf * T + t0) = w;
    }
}

// ---------------- kernel 2: R,P via bf16 MFMA — register-staged, 2-way t-split ----------------
// Block = 4 waves handles TWO bf: wave wid -> bf = bf0+(wid>>1), t-half = wid&1
// (half0: chunks 0-12, half1: chunks 13-24). Grid = BF/2 -> 4 blocks/CU (16 waves, 50%).
// Epilogue: partial accs reduced through the (dead) Z LDS pairwise, then waves 0/2 write.
#define WB3 7680

__global__ __launch_bounds__(256, 3) void rp_mfma_kernel(const float* __restrict__ mr,
                                                         const float* __restrict__ mi,
                                                         const float* __restrict__ W,
                                                         float2* __restrict__ Rout,
                                                         float2* __restrict__ Pout) {
    __shared__ __align__(16) unsigned char SH[4 * WB3];
    const int lane = threadIdx.x & 63;
    const int wid = threadIdx.x >> 6;
    const int bf = blockIdx.x * 2 + (wid >> 1);
    const int half = wid & 1;
    const int ck0 = half ? 13 : 0;
    const int nck = half ? 12 : 13;
    unsigned char* base = SH + wid * WB3;

    const float* mrp = mr + (size_t)bf * C * T;
    const float* mip = mi + (size_t)bf * C * T;
    const float* Wp  = W  + (size_t)bf * T;

    const int q = lane >> 4, col = lane & 15;
    const int pc = lane >> 3, pg = lane & 7;     // phase-B task: channel, 4t-group

    const int PM[6] = {0, 0, 0, 1, 1, 2};
    const int PN[6] = {0, 1, 2, 1, 2, 2};

    // per-lane chunk sources (advance 32 floats per chunk)
    const float* ysr = mrp + pc * T + pg * 4 - 8;
    const float* ysi = mip + pc * T + pg * 4 - 8;
    const float* wsr = Wp + pg * 4;

    f32x4 accRe[6], accIr[6], accRi[6];
#pragma unroll
    for (int p = 0; p < 6; ++p) {
        accRe[p] = (f32x4){0.f, 0.f, 0.f, 0.f};
        accIr[p] = (f32x4){0.f, 0.f, 0.f, 0.f};
        accRi[p] = (f32x4){0.f, 0.f, 0.f, 0.f};
    }

    // prologue: load first chunk (halo clamp only in half 0)
    float4 yr0, yr1, yr2, yi0, yi1, yi2, wcur;
    if (half == 0) {
        const float* cbr = mrp + pc * T;
        const float* cbi = mip + pc * T;
        bool h0 = (pg < 2), h1 = (pg < 1);
        yr0 = *(const float4*)(h0 ? cbr : ysr);
        yr1 = *(const float4*)(h1 ? cbr : (ysr + 4));
        yr2 = *(const float4*)(ysr + 8);
        yi0 = *(const float4*)(h0 ? cbi : ysi);
        yi1 = *(const float4*)(h1 ? cbi : (ysi + 4));
        yi2 = *(const float4*)(ysi + 8);
        wcur = *(const float4*)wsr;
        if (h0) { yr0 = make_float4(0.f,0.f,0.f,0.f); yi0 = make_float4(0.f,0.f,0.f,0.f); }
        if (h1) { yr1 = make_float4(0.f,0.f,0.f,0.f); yi1 = make_float4(0.f,0.f,0.f,0.f); }
    } else {
        int o0 = ck0 * 32;
        yr0 = *(const float4*)(ysr + o0);
        yr1 = *(const float4*)(ysr + o0 + 4);
        yr2 = *(const float4*)(ysr + o0 + 8);
        yi0 = *(const float4*)(ysi + o0);
        yi1 = *(const float4*)(ysi + o0 + 4);
        yi2 = *(const float4*)(ysi + o0 + 8);
        wcur = *(const float4*)(wsr + o0);
    }

    for (int ks = ck0; ks < ck0 + nck; ++ks) {
        // ---- Phase B: build 6 shift-variant bf16 rows from registers ----
        {
            float yre[12], yim[12];
            yre[0] = yr0.x; yre[1] = yr0.y; yre[2]  = yr0.z; yre[3]  = yr0.w;
            yre[4] = yr1.x; yre[5] = yr1.y; yre[6]  = yr1.z; yre[7]  = yr1.w;
            yre[8] = yr2.x; yre[9] = yr2.y; yre[10] = yr2.z; yre[11] = yr2.w;
            yim[0] = yi0.x; yim[1] = yi0.y; yim[2]  = yi0.z; yim[3]  = yi0.w;
            yim[4] = yi1.x; yim[5] = yi1.y; yim[6]  = yi1.z; yim[7]  = yi1.w;
            yim[8] = yi2.x; yim[9] = yi2.y; yim[10] = yi2.z; yim[11] = yi2.w;
            float wv[4] = {wcur.x, wcur.y, wcur.z, wcur.w};
#pragma unroll
            for (int v = 0; v < 6; ++v) {
                int row = (v < 5) ? (v * 8 + pc) : (40 + pc);
                int off = (v < 5) ? (5 - v) : 8;
                bf16x4 zr, zi;
#pragma unroll
                for (int e = 0; e < 4; ++e) {
                    zr[e] = (__bf16)(wv[e] * yre[off + e]);
                    zi[e] = (__bf16)(wv[e] * yim[off + e]);
                }
                *(bf16x4*)(base + row * 80 + pg * 8) = zr;
                *(bf16x4*)(base + 3840 + row * 80 + pg * 8) = zi;
            }
        }

        // ---- issue next chunk's register loads (in flight across fragments + MFMA) ----
        float4 nyr0, nyr1, nyr2, nyi0, nyi1, nyi2, nw;
        if (ks + 1 < ck0 + nck) {
            int off = (ks + 1) * 32;
            nyr0 = *(const float4*)(ysr + off);
            nyr1 = *(const float4*)(ysr + off + 4);
            nyr2 = *(const float4*)(ysr + off + 8);
            nyi0 = *(const float4*)(ysi + off);
            nyi1 = *(const float4*)(ysi + off + 4);
            nyi2 = *(const float4*)(ysi + off + 8);
            nw   = *(const float4*)(wsr + off);
        }

        // ---- fragments (shared A/B operand) + 24 MFMA ----
        bf16x8 fr[3], fi[3];
#pragma unroll
        for (int X = 0; X < 3; ++X) {
            fr[X] = *(const bf16x8*)(base + (X * 16 + col) * 80 + q * 16);
            fi[X] = *(const bf16x8*)(base + 3840 + (X * 16 + col) * 80 + q * 16);
        }
#pragma unroll
        for (int p = 0; p < 6; ++p) {
            int mt = PM[p], nt = PN[p];
            accRe[p] = __builtin_amdgcn_mfma_f32_16x16x32_bf16(fr[mt], fr[nt], accRe[p], 0, 0, 0);
            accRe[p] = __builtin_amdgcn_mfma_f32_16x16x32_bf16(fi[mt], fi[nt], accRe[p], 0, 0, 0);
            accIr[p] = __builtin_amdgcn_mfma_f32_16x16x32_bf16(fi[mt], fr[nt], accIr[p], 0, 0, 0);
            accRi[p] = __builtin_amdgcn_mfma_f32_16x16x32_bf16(fr[mt], fi[nt], accRi[p], 0, 0, 0);
        }

        if (ks + 1 < ck0 + nck) {
            yr0 = nyr0; yr1 = nyr1; yr2 = nyr2;
            yi0 = nyi0; yi1 = nyi1; yi2 = nyi2;
            wcur = nw;
        }
    }

    // ---- cross-wave reduction through dead Z LDS (pairwise, serialized) ----
    __syncthreads();
    float* rbuf = (float*)SH;    // 18432 B needed, 30720 available
#pragma unroll
    for (int pair = 0; pair < 2; ++pair) {
        if (wid == pair * 2 + 1) {
#pragma unroll
            for (int p = 0; p < 6; ++p)
#pragma unroll
                for (int r = 0; r < 4; ++r) {
                    rbuf[((p * 3 + 0) * 4 + r) * 64 + lane] = accRe[p][r];
                    rbuf[((p * 3 + 1) * 4 + r) * 64 + lane] = accIr[p][r];
                    rbuf[((p * 3 + 2) * 4 + r) * 64 + lane] = accRi[p][r];
                }
        }
        __syncthreads();
        if (wid == pair * 2) {
#pragma unroll
            for (int p = 0; p < 6; ++p)
#pragma unroll
                for (int r = 0; r < 4; ++r) {
                    accRe[p][r] += rbuf[((p * 3 + 0) * 4 + r) * 64 + lane];
                    accIr[p][r] += rbuf[((p * 3 + 1) * 4 + r) * 64 + lane];
                    accRi[p][r] += rbuf[((p * 3 + 2) * 4 + r) * 64 + lane];
                }
        }
        __syncthreads();
    }

    // ---- epilogue (waves 0 and 2 hold full sums): D row=(lane>>4)*4+reg, col=lane&15 ----
    if ((wid & 1) == 0) {
        float2* Rp = Rout + (size_t)bf * K * K;
        float2* Pp = Pout + (size_t)bf * K * C;
#pragma unroll
        for (int p = 0; p < 6; ++p) {
            int mt = PM[p], nt = PN[p];
#pragma unroll
            for (int r = 0; r < 4; ++r) {
                int m = mt * 16 + q * 4 + r;
                int n = nt * 16 + col;
                float re = accRe[p][r];
                float im = accIr[p][r] - accRi[p][r];
                if (m < K) {
                    if (n < K) {
                        if (m == n) re += 1e-10f;
                        Rp[m * K + n] = make_float2(re, im);
                    } else {
                        Pp[m * C + (n - K)] = make_float2(re, im);
                    }
                }
                if (mt != nt && m < K && n < K)
                    Rp[n * K + m] = make_float2(re, -im);
            }
        }
    }
}

// ---------------- kernel 3: solve — column-split cooperative GJ, 4 waves/system ----------------
__device__ __forceinline__ float rdlane(float v, int j) {
    return __uint_as_float(__builtin_amdgcn_readlane(__float_as_uint(v), (unsigned)j));
}

__global__ __launch_bounds__(256) void solve_kernel(const float2* __restrict__ Rin,
                                                    const float2* __restrict__ Pin,
                                                    float2* __restrict__ Gout) {
    __shared__ float2 lbuf[2][64];
    const int bf = blockIdx.x;
    const int lane = threadIdx.x & 63;
    const int w = threadIdx.x >> 6;
    const bool act = lane < K;
    const int lr = act ? lane : 0;

    float2 colw[12];
    {
        const float2* Arow = Rin + (size_t)bf * K * K + (size_t)lr * K;
        const float2* Prow = Pin + (size_t)bf * K * C + (size_t)lr * C;
#pragma unroll
        for (int m = 0; m < 10; ++m) {
            float2 v = Arow[4 * m + w];
            colw[m] = act ? v : make_float2(0.f, 0.f);
        }
#pragma unroll
        for (int m = 10; m < 12; ++m) {
            float2 v = Prow[4 * (m - 10) + w];
            colw[m] = act ? v : make_float2(0.f, 0.f);
        }
    }

#pragma unroll
    for (int j = 0; j < K; ++j) {
        const int par = j & 1;
        const int wo = j & 3;       // owner wave (static)
        const int mj = j >> 2;      // owner's local pivot column (static)
        if (w == wo) {
            float dx = rdlane(colw[mj].x, j);
            float dy = rdlane(colw[mj].y, j);
            float den = fmaf(dx, dx, dy * dy);
            float r = 1.0f / den;
            float ix = dx * r, iy = -dy * r;
            float lx = colw[mj].x * ix - colw[mj].y * iy;
            float ly = colw[mj].x * iy + colw[mj].y * ix;
            bool isj = (lane == j);
            lx = isj ? (1.0f - ix) : lx;
            ly = isj ? (0.0f - iy) : ly;
            lbuf[par][lane] = make_float2(lx, ly);
        }
        __syncthreads();
        float2 l = lbuf[par][lane];
#pragma unroll
        for (int m = 0; m < 12; ++m) {
            if (4 * m + 3 <= j) continue;            // statically dead for all waves
            bool doit = (4 * m > j) || (4 * m + w > j);  // first term static
            if (doit) {
                float ux = rdlane(colw[m].x, j);
                float uy = rdlane(colw[m].y, j);
                colw[m].x = fmaf(-l.x, ux, fmaf( l.y, uy, colw[m].x));
                colw[m].y = fmaf(-l.x, uy, fmaf(-l.y, ux, colw[m].y));
            }
        }
    }

    if (act) {
        float2* Gp = Gout + (size_t)bf * K * C + (size_t)lane * C;
        Gp[w]     = colw[10];
        Gp[4 + w] = colw[11];
    }
}

// ---------------- kernel 4: X via bf16 MFMA — 4 splits of one bf packed per block ----------------
#define XSTR 144
#define XWB 12032

__device__ __forceinline__ PF x_load(const float* __restrict__ mrp,
                                     const float* __restrict__ mip,
                                     int tb, int lane) {
    PF p;
#pragma unroll
    for (int it = 0; it < 3; ++it) {
        int task = lane + it * 64;
        float4 v = make_float4(0.f, 0.f, 0.f, 0.f);
        if (task < 160) {
            int pl = task / 80;
            int rem = task - pl * 80;
            int c = rem / 10, grp = rem - c * 10;
            int tg = tb - 8 + grp * 4;
            const float* srcp = pl ? mip : mrp;
            if (tg >= 0) v = *(const float4*)(srcp + c * T + tg);
        }
        p.v[it] = v;
    }
    return p;
}

__device__ __forceinline__ void x_store(const PF& p, float* sre, float* sim_, int lane) {
#pragma unroll
    for (int it = 0; it < 3; ++it) {
        int task = lane + it * 64;
        if (task < 160) {
            int pl = task / 80;
            int rem = task - pl * 80;
            int c = rem / 10, grp = rem - c * 10;
            *(float4*)((pl ? sim_ : sre) + c * 44 + grp * 4) = p.v[it];
        }
    }
}

__global__ __launch_bounds__(256) void x_mfma_kernel(const float* __restrict__ mr,
                                                     const float* __restrict__ mi,
                                                     const float2* __restrict__ Gin,
                                                     const int* __restrict__ ilens,
                                                     float2* __restrict__ out) {
    __shared__ __align__(16) unsigned char SH[4 * XWB];
    const int lane = threadIdx.x & 63;
    const int split = threadIdx.x >> 6;
    const int bf = blockIdx.x;
    const int ck0 = (split == 0) ? 0 : (1 + split * 6);
    const int nck = (split == 0) ? 7 : 6;
    unsigned char* base = SH + split * XWB;
    float* sre = (float*)(base + 9216);
    float* sim_ = (float*)(base + 10624);

    const float* mrp = mr + (size_t)bf * C * T;
    const float* mip = mi + (size_t)bf * C * T;
    const float2* Gp = Gin + (size_t)bf * K * C;
    float2* outp = out + (size_t)bf * C * T;
    const int len = ilens[bf / F];

    const int q = lane >> 4, col = lane & 15;
    const int t2 = lane >> 1, half = lane & 1;

    // ---- one-time: zero-fill bytes [80,128) of all rows (a = 40..63 -> 0.0) ----
#pragma unroll
    for (int pl = 0; pl < 2; ++pl) {
        unsigned char* pb = base + pl * 4608 + t2 * XSTR + 80 + half * 24;
        *(float2*)(pb)      = make_float2(0.f, 0.f);
        *(float2*)(pb + 8)  = make_float2(0.f, 0.f);
        *(float2*)(pb + 16) = make_float2(0.f, 0.f);
    }

    // ---- A fragments: G (and -Gi) in registers, built once ----
    bf16x8 Agr[2], Agi[2], Agin[2];
#pragma unroll
    for (int ks = 0; ks < 2; ++ks)
#pragma unroll
        for (int j = 0; j < 8; ++j) {
            int a = ks * 32 + q * 8 + j;
            float2 g = make_float2(0.f, 0.f);
            if (a < K && col < C) g = Gp[a * C + col];
            Agr[ks][j]  = (__bf16)g.x;
            Agi[ks][j]  = (__bf16)g.y;
            Agin[ks][j] = (__bf16)(-g.y);
        }

    PF cur = x_load(mrp, mip, ck0 * 32, lane);

    for (int ci = 0; ci < nck; ++ci) {
        const int tb = (ck0 + ci) * 32;

        // ---- write staged chunk; prefetch next ----
        x_store(cur, sre, sim_, lane);
        if (ci + 1 < nck) cur = x_load(mrp, mip, tb + 32, lane);

        // ---- Phase B: build transposed bf16 Ytilde rows [t_local][a] ----
#pragma unroll
        for (int i = 0; i < 5; ++i) {
            int abase = half * 20 + 4 * i;
            bf16x4 zr, zi;
#pragma unroll
            for (int e2 = 0; e2 < 4; ++e2) {
                int a = abase + e2;
                int v = a >> 3, c = a & 7;
                int idx = c * 44 + t2 + 5 - v;   // Y[c][tb+t2-3-v]
                zr[e2] = (__bf16)sre[idx];
                zi[e2] = (__bf16)sim_[idx];
            }
            *(bf16x4*)(base + t2 * XSTR + abase * 2) = zr;
            *(bf16x4*)(base + 4608 + t2 * XSTR + abase * 2) = zi;
        }

        // ---- two 16-t tiles: 8 MFMA each + epilogue (Y from scratch LDS) ----
#pragma unroll
        for (int tt = 0; tt < 2; ++tt) {
            const int trow = tt * 16 + col;
            f32x4 accRe = (f32x4){0.f, 0.f, 0.f, 0.f};
            f32x4 accIm = (f32x4){0.f, 0.f, 0.f, 0.f};
#pragma unroll
            for (int ks = 0; ks < 2; ++ks) {
                bf16x8 byr = *(const bf16x8*)(base + trow * XSTR + ks * 64 + q * 16);
                bf16x8 byi = *(const bf16x8*)(base + 4608 + trow * XSTR + ks * 64 + q * 16);
                accRe = __builtin_amdgcn_mfma_f32_16x16x32_bf16(Agr[ks], byr, accRe, 0, 0, 0);
                accRe = __builtin_amdgcn_mfma_f32_16x16x32_bf16(Agi[ks], byi, accRe, 0, 0, 0);
                accIm = __builtin_amdgcn_mfma_f32_16x16x32_bf16(Agr[ks], byi, accIm, 0, 0, 0);
                accIm = __builtin_amdgcn_mfma_f32_16x16x32_bf16(Agin[ks], byr, accIm, 0, 0, 0);
            }
            // D row=(lane>>4)*4+r (=e), col=lane&15 (=t offset) [m89]
            if (q < 2) {
                int t = tb + tt * 16 + col;
                int l = tt * 16 + col + 8;       // scratch index of t
                bool ok = (t < len);
#pragma unroll
                for (int r = 0; r < 4; ++r) {
                    int e = q * 4 + r;
                    float yr = sre[e * 44 + l];
                    float yi = sim_[e * 44 + l];
                    float2 v = ok ? make_float2(yr - accRe[r], yi - accIm[r])
                                  : make_float2(0.f, 0.f);
                    outp[e * T + t] = v;
                }
            }
        }
    }
}

extern "C" void kernel_launch(void* const* d_in, const int* in_sizes, int n_in,
                              void* d_out, int out_size, void* d_ws, size_t ws_size,
                              hipStream_t stream) {
    const float* sep_r = (const float*)d_in[0];
    const float* sep_i = (const float*)d_in[1];
    const float* mix_r = (const float*)d_in[2];
    const float* mix_i = (const float*)d_in[3];
    const int* ilens   = (const int*)d_in[4];

    float* ws = (float*)d_ws;
    float* W = ws;                                        // BF*T floats
    float2* Rws = (float2*)(ws + (size_t)BF * T);         // BF*K*K float2
    float2* Gws = Rws + (size_t)BF * K * K;               // BF*K*C float2 (P then G in-place)

    power_kernel<<<BF, 256, 0, stream>>>(sep_r, sep_i, W);
    rp_mfma_kernel<<<BF / 2, 256, 0, stream>>>(mix_r, mix_i, W, Rws, Gws);
    solve_kernel<<<BF, 256, 0, stream>>>(Rws, Gws, Gws);
    x_mfma_kernel<<<BF, 256, 0, stream>>>(mix_r, mix_i, Gws, ilens, (float2*)d_out);
}